// Round 6
// baseline (102.986 us; speedup 1.0000x reference)
//
#include <hip/hip_runtime.h>
#include <math.h>

#define NATOMS   4096
#define NRBF     16
#define NHID     64
#define CUTOFF2  25.0f
// ETA = 0.5*(5.0-0.5)/16 = 0.140625 ; 1/(2*ETA^2)
#define INV_2ETA2 25.283950617283951f
#define PI_OVER_CUTOFF 0.62831853071795865f  // pi / 5
#define CAP      96     // per-wave neighbor capacity (empirically OK: r2/r3 passed)
#define NBLOCKS  (NATOMS / 4)   // 1024 main-kernel blocks
#define NGROUPS  16             // completion-tree groups of 64 blocks

// ---- cell list (box 40, cutoff 5 -> 8^3 cells, lambda = 8 atoms/cell) ----
#define NC1      8
#define NCELLS   512
#define CELLCAP  32      // empirically sufficient (r2/r3 passed, absmax 0)
#define INV_CELL 0.2f    // 1 / 5.0

// ws layout (float/int units):
//   [0, 1024)         per-block partial energies (float)
//   [1024, 1040)      gsum[16] group sums (float)
//   [2048 + g*32]     gdone[g] group counters, one per 128B line (int)
//   [2048 + 512]      gdone2 second-level counter (int)
//   [4096, 4609)      cnt[513] (cell 512 = dummy, always 0)
//   [5120, 5120+512*32*4)  cells: float4[NCELLS][CELLCAP]
#define WS_PART_OFF   0
#define WS_GSUM_OFF   1024
#define WS_GDONE_OFF  2048
#define WS_CNT_OFF    4096
#define WS_CELLS_OFF  5120
#define WS_NEED_BYTES ((size_t)(WS_CELLS_OFF + NCELLS * CELLCAP * 4) * 4)

// ============================ cell-list path ============================

// Single block, 1024 threads: zero counters in LDS, bin all 4096 atoms via
// LDS atomics, flush cnt/cells to global, zero the completion-tree counters.
__global__ __launch_bounds__(1024) void bin1_kernel(
    const float* __restrict__ pos,
    int* __restrict__ cnt,           // 513 ints
    int* __restrict__ gdone,         // tree counters (stride 32, +[512])
    float4* __restrict__ cells)
{
    __shared__ int lcnt[NCELLS + 1];
    const int tid = threadIdx.x;
    if (tid < NCELLS + 1) lcnt[tid] = 0;
    __syncthreads();

    // thread t owns atoms 4t..4t+3 : 3 coalesced float4 loads, register unpack
    const float4* src = (const float4*)pos;
    const float4 v0 = src[3 * tid + 0];  // x0 y0 z0 x1
    const float4 v1 = src[3 * tid + 1];  // y1 z1 x2 y2
    const float4 v2 = src[3 * tid + 2];  // z2 x3 y3 z3
    const float xs[4] = {v0.x, v0.w, v1.z, v2.y};
    const float ys[4] = {v0.y, v1.x, v1.w, v2.z};
    const float zs[4] = {v0.z, v1.y, v2.x, v2.w};
#pragma unroll
    for (int u = 0; u < 4; ++u) {
        const int cx = min((int)(xs[u] * INV_CELL), NC1 - 1);
        const int cy = min((int)(ys[u] * INV_CELL), NC1 - 1);
        const int cz = min((int)(zs[u] * INV_CELL), NC1 - 1);
        const int c  = (cz * NC1 + cy) * NC1 + cx;
        const int slot = atomicAdd(&lcnt[c], 1);          // LDS atomic
        if (slot < CELLCAP)
            cells[c * CELLCAP + slot] = make_float4(xs[u], ys[u], zs[u], 0.0f);
    }
    __syncthreads();
    if (tid < NCELLS + 1) cnt[tid] = lcnt[tid];
    if (tid < NGROUPS)    gdone[tid * 32] = 0;   // each counter own 128B line
    if (tid == NGROUPS)   gdone[512] = 0;        // second-level counter
}

// One wave per atom; sieve = 27 neighbor cells (2 cells/iter, 32 lanes each).
// Epilogue: two-level completion tree (16 groups x 64 blocks) — max 64
// same-address RMWs per counter instead of 1024 (r3's ~30us serialization).
__global__ __launch_bounds__(256) void short_range_cells_kernel(
    const float* __restrict__ pos,
    const float* __restrict__ centers,
    const int* __restrict__ cnt,
    int* __restrict__ gdone,
    const float4* __restrict__ cells,
    const float* __restrict__ W1, const float* __restrict__ b1,
    const float* __restrict__ W2, const float* __restrict__ b2,
    const float* __restrict__ W3, const float* __restrict__ b3,
    float* __restrict__ ws,          // partials [0,1024) ; gsum at [1024,1040)
    float* __restrict__ out)
{
    __shared__ float sdist[4][CAP];     // 1.5 KB
    __shared__ float s_h1[4][NHID];     // 1 KB
    __shared__ float s_part[4];
    __shared__ int   s_role;

    const int tid  = threadIdx.x;
    const int lane = tid & 63;
    const int wave = tid >> 6;
    const int i    = blockIdx.x * 4 + wave;   // this wave's atom

    const float xi = pos[3 * i + 0];
    const float yi = pos[3 * i + 1];
    const float zi = pos[3 * i + 2];
    const int cxi = min((int)(xi * INV_CELL), NC1 - 1);
    const int cyi = min((int)(yi * INV_CELL), NC1 - 1);
    const int czi = min((int)(zi * INV_CELL), NC1 - 1);

    // lane l < 27 owns neighbor cell l (3x3x3); others own dummy cell 512
    // whose cnt is always 0.
    int nc = NCELLS;
    if (lane < 27) {
        const int cx = cxi + (lane % 3) - 1;
        const int cy = cyi + ((lane / 3) % 3) - 1;
        const int cz = czi + (lane / 9) - 1;
        if ((unsigned)cx < (unsigned)NC1 && (unsigned)cy < (unsigned)NC1 &&
            (unsigned)cz < (unsigned)NC1)
            nc = (cz * NC1 + cy) * NC1 + cx;
    }
    const int mycnt = min(cnt[nc], CELLCAP);

    // ---- sieve: 14 iterations x 2 cells; ballot + prefix compaction ----
    const int half = lane >> 5;   // which cell of the pair
    const int idx  = lane & 31;   // slot within that cell
    int base = 0;
#pragma unroll
    for (int t = 0; t < 14; ++t) {
        const int cl = 2 * t + half;               // 0..27 (27 -> dummy lane)
        const int c  = __shfl(nc,    cl, 64);
        const int cn = __shfl(mycnt, cl, 64);
        float sq = 1e30f;
        bool pass = false;
        if (idx < cn) {
            const float4 p = cells[c * CELLCAP + idx];
            const float dx = p.x - xi;
            const float dy = p.y - yi;
            const float dz = p.z - zi;
            sq = dx * dx + dy * dy + dz * dz;
            pass = (sq > 0.0f) && (sq < CUTOFF2);
        }
        const unsigned long long m = __ballot(pass);
        if (pass) {
            const int slot = base + (int)__popcll(m & ((1ull << lane) - 1ull));
            if (slot < CAP) sdist[wave][slot] = sqrtf(sq);
        }
        base += (int)__popcll(m);
    }
    const int count = min(base, CAP);

    // ---- dense RBF, transposed: entry = e0 + (lane>>4), feature = lane&15 ----
    const int   kf   = lane & 15;
    const int   eoff = lane >> 4;
    const float ck   = centers[kf];
    float acc = 0.0f;
    for (int e0 = 0; e0 < count; e0 += 4) {
        const int e = e0 + eoff;
        if (e < count) {
            const float d = sdist[wave][e];
            const float w = 0.5f * (1.0f + __cosf(d * PI_OVER_CUTOFF));
            const float t = d - ck;
            acc += w * __expf(-(t * t) * INV_2ETA2);
        }
    }
    acc += __shfl_xor(acc, 16, 64);
    acc += __shfl_xor(acc, 32, 64);

    // ---- per-wave MLP: lane n owns hidden unit n (NHID == 64) ----
    float h = b1[lane];
#pragma unroll
    for (int k = 0; k < NRBF; ++k)
        h += __shfl(acc, k, 64) * W1[k * NHID + lane];   // broadcast feat[k]
    h = h / (1.0f + __expf(-h));         // silu
    s_h1[wave][lane] = h;
    // single-wave producer/consumer on own LDS row: program order suffices
    float h2 = b2[lane];
#pragma unroll 8
    for (int m = 0; m < NHID; ++m) h2 += s_h1[wave][m] * W2[m * NHID + lane];
    h2 = h2 / (1.0f + __expf(-h2));      // silu
    float e = h2 * W3[lane];
#pragma unroll
    for (int off = 32; off > 0; off >>= 1) e += __shfl_xor(e, off, 64);
    if (lane == 0) s_part[wave] = e;
    __syncthreads();

    // ---- completion tree ----
    const int g = blockIdx.x >> 6;              // group of 64 blocks
    if (tid == 0) {
        const float p = s_part[0] + s_part[1] + s_part[2] + s_part[3];
        __hip_atomic_store(&ws[blockIdx.x], p, __ATOMIC_RELEASE,
                           __HIP_MEMORY_SCOPE_AGENT);
        const int old = __hip_atomic_fetch_add(&gdone[g * 32], 1,
                                               __ATOMIC_ACQ_REL,
                                               __HIP_MEMORY_SCOPE_AGENT);
        s_role = (old == 63);
    }
    __syncthreads();
    if (s_role && wave == 0) {
        // last block of group g: sum its 64 partials (RMW release-sequence
        // on gdone[g] makes all 64 release-stores visible)
        float v = __hip_atomic_load(&ws[g * 64 + lane], __ATOMIC_RELAXED,
                                    __HIP_MEMORY_SCOPE_AGENT);
#pragma unroll
        for (int off = 32; off > 0; off >>= 1) v += __shfl_xor(v, off, 64);
        int last2 = 0;
        if (lane == 0) {
            __hip_atomic_store(&ws[WS_GSUM_OFF + g], v, __ATOMIC_RELEASE,
                               __HIP_MEMORY_SCOPE_AGENT);
            const int old2 = __hip_atomic_fetch_add(&gdone[512], 1,
                                                    __ATOMIC_ACQ_REL,
                                                    __HIP_MEMORY_SCOPE_AGENT);
            last2 = (old2 == NGROUPS - 1);
        }
        last2 = __shfl(last2, 0, 64);
        if (last2) {
            float t = (lane < NGROUPS)
                    ? __hip_atomic_load(&ws[WS_GSUM_OFF + lane],
                                        __ATOMIC_RELAXED,
                                        __HIP_MEMORY_SCOPE_AGENT)
                    : 0.0f;
#pragma unroll
            for (int off = 32; off > 0; off >>= 1) t += __shfl_xor(t, off, 64);
            if (lane == 0)
                out[0] = t + (float)NATOMS * b3[0];
        }
    }
}

// ==================== fallback: previous verified path ====================
// (verbatim 83 us kernel; used only if ws_size < WS_NEED_BYTES)

#define CHUNK 1024

__global__ __launch_bounds__(256) void short_range_fb_kernel(
    const float* __restrict__ pos,
    const float* __restrict__ centers,
    const float* __restrict__ W1, const float* __restrict__ b1,
    const float* __restrict__ W2, const float* __restrict__ b2,
    const float* __restrict__ W3,
    float* __restrict__ ws)
{
    __shared__ float spos[3 * CHUNK];
    __shared__ float sdist[4][CAP];
    __shared__ float s_h1[4][NHID];
    __shared__ float s_part[4];

    const int tid  = threadIdx.x;
    const int lane = tid & 63;
    const int wave = tid >> 6;
    const int i    = blockIdx.x * 4 + wave;

    float* sx = spos;
    float* sy = spos + CHUNK;
    float* sz = spos + 2 * CHUNK;

    const float xi = pos[3 * i + 0];
    const float yi = pos[3 * i + 1];
    const float zi = pos[3 * i + 2];

    int base = 0;
    for (int c = 0; c < 4; ++c) {
        {
            const float4* src = (const float4*)(pos + c * (3 * CHUNK));
            const float4 v0 = src[3 * tid + 0];
            const float4 v1 = src[3 * tid + 1];
            const float4 v2 = src[3 * tid + 2];
            *(float4*)&sx[4 * tid] = make_float4(v0.x, v0.w, v1.z, v2.y);
            *(float4*)&sy[4 * tid] = make_float4(v0.y, v1.x, v1.w, v2.z);
            *(float4*)&sz[4 * tid] = make_float4(v0.z, v1.y, v2.x, v2.w);
        }
        __syncthreads();
#pragma unroll
        for (int it = 0; it < 4; ++it) {
            const int a = it * 256 + lane * 4;
            const float4 vx = *(const float4*)&sx[a];
            const float4 vy = *(const float4*)&sy[a];
            const float4 vz = *(const float4*)&sz[a];
#pragma unroll
            for (int u = 0; u < 4; ++u) {
                const float dx = ((const float*)&vx)[u] - xi;
                const float dy = ((const float*)&vy)[u] - yi;
                const float dz = ((const float*)&vz)[u] - zi;
                const float sq = dx * dx + dy * dy + dz * dz;
                const bool pass = (sq > 0.0f) && (sq < CUTOFF2);
                const unsigned long long mask = __ballot(pass);
                if (pass) {
                    const int slot = base + (int)__popcll(mask & ((1ull << lane) - 1ull));
                    if (slot < CAP) sdist[wave][slot] = sqrtf(sq);
                }
                base += (int)__popcll(mask);
            }
        }
        __syncthreads();
    }
    const int count = min(base, CAP);

    const int   kf   = lane & 15;
    const int   eoff = lane >> 4;
    const float ck   = centers[kf];
    float acc = 0.0f;
    for (int e0 = 0; e0 < count; e0 += 4) {
        const int e = e0 + eoff;
        if (e < count) {
            const float d = sdist[wave][e];
            const float w = 0.5f * (1.0f + __cosf(d * PI_OVER_CUTOFF));
            const float t = d - ck;
            acc += w * __expf(-(t * t) * INV_2ETA2);
        }
    }
    acc += __shfl_xor(acc, 16, 64);
    acc += __shfl_xor(acc, 32, 64);

    float h = b1[lane];
#pragma unroll
    for (int k = 0; k < NRBF; ++k)
        h += __shfl(acc, k, 64) * W1[k * NHID + lane];
    h = h / (1.0f + __expf(-h));
    s_h1[wave][lane] = h;
    float h2 = b2[lane];
#pragma unroll 8
    for (int m = 0; m < NHID; ++m) h2 += s_h1[wave][m] * W2[m * NHID + lane];
    h2 = h2 / (1.0f + __expf(-h2));
    float e = h2 * W3[lane];
#pragma unroll
    for (int off = 32; off > 0; off >>= 1) e += __shfl_xor(e, off, 64);
    if (lane == 0) s_part[wave] = e;
    __syncthreads();
    if (tid == 0)
        ws[blockIdx.x] = s_part[0] + s_part[1] + s_part[2] + s_part[3];
}

__global__ __launch_bounds__(256) void reduce_fb_kernel(
    const float* __restrict__ ws, const float* __restrict__ b3,
    float* __restrict__ out)
{
    __shared__ float s_part[4];
    const int tid  = threadIdx.x;
    const int lane = tid & 63;
    const int wave = tid >> 6;

    const float4 v = ((const float4*)ws)[tid];
    float s = v.x + v.y + v.z + v.w;
#pragma unroll
    for (int off = 32; off > 0; off >>= 1) s += __shfl_xor(s, off, 64);
    if (lane == 0) s_part[wave] = s;
    __syncthreads();
    if (tid == 0)
        out[0] = s_part[0] + s_part[1] + s_part[2] + s_part[3]
               + (float)NATOMS * b3[0];
}

// ============================== launch ==============================

extern "C" void kernel_launch(void* const* d_in, const int* in_sizes, int n_in,
                              void* d_out, int out_size, void* d_ws, size_t ws_size,
                              hipStream_t stream) {
    const float* pos     = (const float*)d_in[0];
    const float* centers = (const float*)d_in[1];
    const float* W1      = (const float*)d_in[2];
    const float* b1      = (const float*)d_in[3];
    const float* W2      = (const float*)d_in[4];
    const float* b2      = (const float*)d_in[5];
    const float* W3      = (const float*)d_in[6];
    const float* b3      = (const float*)d_in[7];
    float* out = (float*)d_out;
    float* ws  = (float*)d_ws;

    if (ws_size >= WS_NEED_BYTES) {
        int*    cnt   = (int*)(ws + WS_CNT_OFF);
        int*    gdone = (int*)(ws + WS_GDONE_OFF);
        float4* cells = (float4*)(ws + WS_CELLS_OFF);
        hipLaunchKernelGGL(bin1_kernel, dim3(1), dim3(1024), 0, stream,
                           pos, cnt, gdone, cells);
        hipLaunchKernelGGL(short_range_cells_kernel, dim3(NBLOCKS), dim3(256), 0, stream,
                           pos, centers, cnt, gdone, cells,
                           W1, b1, W2, b2, W3, b3,
                           ws, out);
    } else {
        // workspace too small for cell lists: previous verified path
        hipLaunchKernelGGL(short_range_fb_kernel, dim3(NATOMS / 4), dim3(256), 0, stream,
                           pos, centers, W1, b1, W2, b2, W3, ws);
        hipLaunchKernelGGL(reduce_fb_kernel, dim3(1), dim3(256), 0, stream,
                           ws, b3, out);
    }
}

// Round 9
// 80.583 us; speedup vs baseline: 1.2780x; 1.2780x over previous
//
#include <hip/hip_runtime.h>
#include <math.h>

#define NATOMS   4096
#define NRBF     16
#define NHID     64
#define CUTOFF2  25.0f
// ETA = 0.5*(5.0-0.5)/16 = 0.140625 ; 1/(2*ETA^2)
#define INV_2ETA2 25.283950617283951f
#define PI_OVER_CUTOFF 0.62831853071795865f  // pi / 5
#define CAP      96     // per-wave neighbor capacity (empirically OK: r2/r3/r6 passed)

// ---- cell list (box 40, cutoff 5 -> 8^3 cells, lambda = 8 atoms/cell) ----
#define NC1      8
#define NCELLS   512
#define CELLCAP  32      // empirically sufficient (r2/r3/r6 passed, absmax 0)
#define INV_CELL 0.2f    // 1 / 5.0

// ws layout (float units):
//   [0, 4096)              per-atom energies (float)
//   [4096, 4609)           cnt[513] ints (cell 512 = dummy, always 0)
//   [5120, 5120+512*32*4)  cells: float4[NCELLS][CELLCAP]
#define WS_ENERGY_OFF 0
#define WS_CNT_OFF    4096
#define WS_CELLS_OFF  5120
#define WS_NEED_BYTES ((size_t)(WS_CELLS_OFF + NCELLS * CELLCAP * 4) * 4)

// ============================ cell-list path ============================

// Single block, 1024 threads: zero counters in LDS, bin all 4096 atoms via
// LDS atomics, flush cnt/cells to global. Self-zeroing -> no memset dispatch.
// NO device-scope atomics anywhere in this path (r3/r6 lesson: the fused
// agent-scope epilogue cost ~17us regardless of fan-in).
__global__ __launch_bounds__(1024) void bin1_kernel(
    const float* __restrict__ pos,
    int* __restrict__ cnt,           // 513 ints
    float4* __restrict__ cells)
{
    __shared__ int lcnt[NCELLS + 1];
    const int tid = threadIdx.x;
    if (tid < NCELLS + 1) lcnt[tid] = 0;
    __syncthreads();

    // thread t owns atoms 4t..4t+3 : 3 coalesced float4 loads, register unpack
    const float4* src = (const float4*)pos;
    const float4 v0 = src[3 * tid + 0];  // x0 y0 z0 x1
    const float4 v1 = src[3 * tid + 1];  // y1 z1 x2 y2
    const float4 v2 = src[3 * tid + 2];  // z2 x3 y3 z3
    const float xs[4] = {v0.x, v0.w, v1.z, v2.y};
    const float ys[4] = {v0.y, v1.x, v1.w, v2.z};
    const float zs[4] = {v0.z, v1.y, v2.x, v2.w};
#pragma unroll
    for (int u = 0; u < 4; ++u) {
        const int cx = min((int)(xs[u] * INV_CELL), NC1 - 1);
        const int cy = min((int)(ys[u] * INV_CELL), NC1 - 1);
        const int cz = min((int)(zs[u] * INV_CELL), NC1 - 1);
        const int c  = (cz * NC1 + cy) * NC1 + cx;
        const int slot = atomicAdd(&lcnt[c], 1);          // LDS atomic
        if (slot < CELLCAP)
            cells[c * CELLCAP + slot] = make_float4(xs[u], ys[u], zs[u], 0.0f);
    }
    __syncthreads();
    if (tid < NCELLS + 1) cnt[tid] = lcnt[tid];
}

// One wave per atom; sieve = 27 neighbor cells (2 cells/iter, 32 lanes each;
// CELLCAP=32 guarantees fit). No barriers, no global atomics: waves are fully
// independent, per-wave energy -> ws[i]. (Verbatim r2 main, measured 85.7us
// total in the 4-dispatch shape.)
__global__ __launch_bounds__(256) void short_range_cells_kernel(
    const float* __restrict__ pos,
    const float* __restrict__ centers,
    const int* __restrict__ cnt,
    const float4* __restrict__ cells,
    const float* __restrict__ W1, const float* __restrict__ b1,
    const float* __restrict__ W2, const float* __restrict__ b2,
    const float* __restrict__ W3,
    float* __restrict__ ws)
{
    __shared__ float sdist[4][CAP];     // 1.5 KB
    __shared__ float s_h1[4][NHID];     // 1 KB

    const int tid  = threadIdx.x;
    const int lane = tid & 63;
    const int wave = tid >> 6;
    const int i    = blockIdx.x * 4 + wave;   // this wave's atom

    const float xi = pos[3 * i + 0];
    const float yi = pos[3 * i + 1];
    const float zi = pos[3 * i + 2];
    const int cxi = min((int)(xi * INV_CELL), NC1 - 1);
    const int cyi = min((int)(yi * INV_CELL), NC1 - 1);
    const int czi = min((int)(zi * INV_CELL), NC1 - 1);

    // lane l < 27 owns neighbor cell l (3x3x3); others own dummy cell 512
    // whose cnt is always 0.
    int nc = NCELLS;
    if (lane < 27) {
        const int cx = cxi + (lane % 3) - 1;
        const int cy = cyi + ((lane / 3) % 3) - 1;
        const int cz = czi + (lane / 9) - 1;
        if ((unsigned)cx < (unsigned)NC1 && (unsigned)cy < (unsigned)NC1 &&
            (unsigned)cz < (unsigned)NC1)
            nc = (cz * NC1 + cy) * NC1 + cx;
    }
    const int mycnt = min(cnt[nc], CELLCAP);   // broadcast loads; cnt[512]==0

    // ---- sieve: 14 iterations x 2 cells; ballot + prefix compaction ----
    const int half = lane >> 5;   // which cell of the pair
    const int idx  = lane & 31;   // slot within that cell
    int base = 0;
#pragma unroll
    for (int t = 0; t < 14; ++t) {
        const int cl = 2 * t + half;               // 0..27 (27 -> dummy lane)
        const int c  = __shfl(nc,    cl, 64);
        const int cn = __shfl(mycnt, cl, 64);
        float sq = 1e30f;
        bool pass = false;
        if (idx < cn) {
            const float4 p = cells[c * CELLCAP + idx];
            const float dx = p.x - xi;
            const float dy = p.y - yi;
            const float dz = p.z - zi;
            sq = dx * dx + dy * dy + dz * dz;
            pass = (sq > 0.0f) && (sq < CUTOFF2);
        }
        const unsigned long long m = __ballot(pass);
        if (pass) {
            const int slot = base + (int)__popcll(m & ((1ull << lane) - 1ull));
            if (slot < CAP) sdist[wave][slot] = sqrtf(sq);
        }
        base += (int)__popcll(m);
    }
    const int count = min(base, CAP);

    // ---- dense RBF, transposed: entry = e0 + (lane>>4), feature = lane&15 ----
    const int   kf   = lane & 15;
    const int   eoff = lane >> 4;
    const float ck   = centers[kf];
    float acc = 0.0f;
    for (int e0 = 0; e0 < count; e0 += 4) {
        const int e = e0 + eoff;
        if (e < count) {
            const float d = sdist[wave][e];
            const float w = 0.5f * (1.0f + __cosf(d * PI_OVER_CUTOFF));
            const float t = d - ck;
            acc += w * __expf(-(t * t) * INV_2ETA2);
        }
    }
    acc += __shfl_xor(acc, 16, 64);
    acc += __shfl_xor(acc, 32, 64);

    // ---- per-wave MLP: lane n owns hidden unit n (NHID == 64) ----
    float h = b1[lane];
#pragma unroll
    for (int k = 0; k < NRBF; ++k)
        h += __shfl(acc, k, 64) * W1[k * NHID + lane];   // broadcast feat[k]
    h = h / (1.0f + __expf(-h));         // silu
    s_h1[wave][lane] = h;
    // single-wave producer/consumer on own LDS row: program order suffices
    float h2 = b2[lane];
#pragma unroll 8
    for (int m = 0; m < NHID; ++m) h2 += s_h1[wave][m] * W2[m * NHID + lane];
    h2 = h2 / (1.0f + __expf(-h2));      // silu
    float e = h2 * W3[lane];
#pragma unroll
    for (int off = 32; off > 0; off >>= 1) e += __shfl_xor(e, off, 64);
    if (lane == 0) ws[i] = e;
}

// Sum 4096 per-atom energies + NATOMS*b3 -> out[0]. One block. (Verbatim r2.)
__global__ __launch_bounds__(256) void reduce4k_kernel(
    const float* __restrict__ ws, const float* __restrict__ b3,
    float* __restrict__ out)
{
    __shared__ float s_part[4];
    const int tid  = threadIdx.x;
    const int lane = tid & 63;
    const int wave = tid >> 6;

    const float4* v4 = (const float4*)ws;
    float s = 0.0f;
#pragma unroll
    for (int k = 0; k < 4; ++k) {
        const float4 v = v4[tid + 256 * k];   // 1024 float4 = 4096 floats
        s += v.x + v.y + v.z + v.w;
    }
#pragma unroll
    for (int off = 32; off > 0; off >>= 1) s += __shfl_xor(s, off, 64);
    if (lane == 0) s_part[wave] = s;
    __syncthreads();
    if (tid == 0)
        out[0] = s_part[0] + s_part[1] + s_part[2] + s_part[3]
               + (float)NATOMS * b3[0];
}

// ==================== fallback: previous verified path ====================
// (verbatim 83 us kernel; used only if ws_size < WS_NEED_BYTES)

#define CHUNK 1024

__global__ __launch_bounds__(256) void short_range_fb_kernel(
    const float* __restrict__ pos,
    const float* __restrict__ centers,
    const float* __restrict__ W1, const float* __restrict__ b1,
    const float* __restrict__ W2, const float* __restrict__ b2,
    const float* __restrict__ W3,
    float* __restrict__ ws)
{
    __shared__ float spos[3 * CHUNK];
    __shared__ float sdist[4][CAP];
    __shared__ float s_h1[4][NHID];
    __shared__ float s_part[4];

    const int tid  = threadIdx.x;
    const int lane = tid & 63;
    const int wave = tid >> 6;
    const int i    = blockIdx.x * 4 + wave;

    float* sx = spos;
    float* sy = spos + CHUNK;
    float* sz = spos + 2 * CHUNK;

    const float xi = pos[3 * i + 0];
    const float yi = pos[3 * i + 1];
    const float zi = pos[3 * i + 2];

    int base = 0;
    for (int c = 0; c < 4; ++c) {
        {
            const float4* src = (const float4*)(pos + c * (3 * CHUNK));
            const float4 v0 = src[3 * tid + 0];
            const float4 v1 = src[3 * tid + 1];
            const float4 v2 = src[3 * tid + 2];
            *(float4*)&sx[4 * tid] = make_float4(v0.x, v0.w, v1.z, v2.y);
            *(float4*)&sy[4 * tid] = make_float4(v0.y, v1.x, v1.w, v2.z);
            *(float4*)&sz[4 * tid] = make_float4(v0.z, v1.y, v2.x, v2.w);
        }
        __syncthreads();
#pragma unroll
        for (int it = 0; it < 4; ++it) {
            const int a = it * 256 + lane * 4;
            const float4 vx = *(const float4*)&sx[a];
            const float4 vy = *(const float4*)&sy[a];
            const float4 vz = *(const float4*)&sz[a];
#pragma unroll
            for (int u = 0; u < 4; ++u) {
                const float dx = ((const float*)&vx)[u] - xi;
                const float dy = ((const float*)&vy)[u] - yi;
                const float dz = ((const float*)&vz)[u] - zi;
                const float sq = dx * dx + dy * dy + dz * dz;
                const bool pass = (sq > 0.0f) && (sq < CUTOFF2);
                const unsigned long long mask = __ballot(pass);
                if (pass) {
                    const int slot = base + (int)__popcll(mask & ((1ull << lane) - 1ull));
                    if (slot < CAP) sdist[wave][slot] = sqrtf(sq);
                }
                base += (int)__popcll(mask);
            }
        }
        __syncthreads();
    }
    const int count = min(base, CAP);

    const int   kf   = lane & 15;
    const int   eoff = lane >> 4;
    const float ck   = centers[kf];
    float acc = 0.0f;
    for (int e0 = 0; e0 < count; e0 += 4) {
        const int e = e0 + eoff;
        if (e < count) {
            const float d = sdist[wave][e];
            const float w = 0.5f * (1.0f + __cosf(d * PI_OVER_CUTOFF));
            const float t = d - ck;
            acc += w * __expf(-(t * t) * INV_2ETA2);
        }
    }
    acc += __shfl_xor(acc, 16, 64);
    acc += __shfl_xor(acc, 32, 64);

    float h = b1[lane];
#pragma unroll
    for (int k = 0; k < NRBF; ++k)
        h += __shfl(acc, k, 64) * W1[k * NHID + lane];
    h = h / (1.0f + __expf(-h));
    s_h1[wave][lane] = h;
    float h2 = b2[lane];
#pragma unroll 8
    for (int m = 0; m < NHID; ++m) h2 += s_h1[wave][m] * W2[m * NHID + lane];
    h2 = h2 / (1.0f + __expf(-h2));
    float e = h2 * W3[lane];
#pragma unroll
    for (int off = 32; off > 0; off >>= 1) e += __shfl_xor(e, off, 64);
    if (lane == 0) s_part[wave] = e;
    __syncthreads();
    if (tid == 0)
        ws[blockIdx.x] = s_part[0] + s_part[1] + s_part[2] + s_part[3];
}

__global__ __launch_bounds__(256) void reduce_fb_kernel(
    const float* __restrict__ ws, const float* __restrict__ b3,
    float* __restrict__ out)
{
    __shared__ float s_part[4];
    const int tid  = threadIdx.x;
    const int lane = tid & 63;
    const int wave = tid >> 6;

    const float4 v = ((const float4*)ws)[tid];
    float s = v.x + v.y + v.z + v.w;
#pragma unroll
    for (int off = 32; off > 0; off >>= 1) s += __shfl_xor(s, off, 64);
    if (lane == 0) s_part[wave] = s;
    __syncthreads();
    if (tid == 0)
        out[0] = s_part[0] + s_part[1] + s_part[2] + s_part[3]
               + (float)NATOMS * b3[0];
}

// ============================== launch ==============================

extern "C" void kernel_launch(void* const* d_in, const int* in_sizes, int n_in,
                              void* d_out, int out_size, void* d_ws, size_t ws_size,
                              hipStream_t stream) {
    const float* pos     = (const float*)d_in[0];
    const float* centers = (const float*)d_in[1];
    const float* W1      = (const float*)d_in[2];
    const float* b1      = (const float*)d_in[3];
    const float* W2      = (const float*)d_in[4];
    const float* b2      = (const float*)d_in[5];
    const float* W3      = (const float*)d_in[6];
    const float* b3      = (const float*)d_in[7];
    float* out = (float*)d_out;
    float* ws  = (float*)d_ws;

    if (ws_size >= WS_NEED_BYTES) {
        int*    cnt   = (int*)(ws + WS_CNT_OFF);
        float4* cells = (float4*)(ws + WS_CELLS_OFF);
        hipLaunchKernelGGL(bin1_kernel, dim3(1), dim3(1024), 0, stream,
                           pos, cnt, cells);
        hipLaunchKernelGGL(short_range_cells_kernel, dim3(NATOMS / 4), dim3(256), 0, stream,
                           pos, centers, cnt, cells, W1, b1, W2, b2, W3,
                           ws + WS_ENERGY_OFF);
        hipLaunchKernelGGL(reduce4k_kernel, dim3(1), dim3(256), 0, stream,
                           ws + WS_ENERGY_OFF, b3, out);
    } else {
        // workspace too small for cell lists: previous verified path
        hipLaunchKernelGGL(short_range_fb_kernel, dim3(NATOMS / 4), dim3(256), 0, stream,
                           pos, centers, W1, b1, W2, b2, W3, ws);
        hipLaunchKernelGGL(reduce_fb_kernel, dim3(1), dim3(256), 0, stream,
                           ws, b3, out);
    }
}